// Round 8
// baseline (150.106 us; speedup 1.0000x reference)
//
#include <hip/hip_runtime.h>
#include <hip/hip_bf16.h>

#define B_ 2
#define R_ 1
#define A_ 16
#define S_ 14
#define F_ 1024
#define N_ 512
#define D_ (S_*N_)        // 7168
#define M_ (B_*R_*A_)     // 32
#define KK_ (2*D_)        // 14336
#define BE 64
#define ETILES (D_/BE)    // 112

typedef __attribute__((ext_vector_type(8))) short bf16x8;
typedef __attribute__((ext_vector_type(4))) float f32x4;

static __device__ inline short f2bf(float f) {
    __hip_bfloat16 h = __float2bfloat16(f);
    return *reinterpret_cast<short*>(&h);
}
static __device__ inline float bf2f(short s) {
    unsigned int u = ((unsigned int)(unsigned short)s) << 16;
    return __uint_as_float(u);
}

#define LDSP(p) ((__attribute__((address_space(3))) void*)(p))
#define GLBP(p) ((const __attribute__((address_space(1))) void*)(p))

// Build packed A' in 16B-unit-transposed layout: Ap[(g*64 + r)*8 + (k&7)], g=k/8.
// rows 0..31: [yr|yi], rows 32..63: [yi|-yr]. One thread per (m,d): 2 reads, 4 writes.
__global__ void prep_kernel(const float* __restrict__ xr, const float* __restrict__ xi,
                            const int* __restrict__ sc, short* __restrict__ Ap) {
    int idx = blockIdx.x * blockDim.x + threadIdx.x;
    if (idx >= 32 * D_) return;
    int d = idx % D_;
    int m = idx / D_;
    int s = d >> 9;
    int n = d & 511;
    int f = sc[n];
    float vr = xr[(m * S_ + s) * F_ + f];
    float vi = xi[(m * S_ + s) * F_ + f];
    int g1 = d >> 3, j = d & 7;
    int g2 = (D_ + d) >> 3;
    // k = d (first col-half): row m <- vr ; row 32+m <- vi
    Ap[((size_t)g1 * 64 + m) * 8 + j]      = f2bf(vr);
    Ap[((size_t)g1 * 64 + 32 + m) * 8 + j] = f2bf(vi);
    // k = D+d (second col-half): row m <- vi ; row 32+m <- -vr
    Ap[((size_t)g2 * 64 + m) * 8 + j]      = f2bf(vi);
    Ap[((size_t)g2 * 64 + 32 + m) * 8 + j] = f2bf(-vr);
}

// inv[f] = n if sc[n]==f else -1  (single block)
__global__ void inv_kernel(const int* __restrict__ sc, int* __restrict__ inv) {
    int t = threadIdx.x;
    inv[t] = -1;
    __syncthreads();
    if (t < N_) inv[sc[t]] = t;
}

__global__ void zero_kernel(float4* __restrict__ out, int n4) {
    int i = blockIdx.x * blockDim.x + threadIdx.x;
    if (i < n4) out[i] = make_float4(0.f, 0.f, 0.f, 0.f);
}

// -------- all-register GEMM: no LDS, no barriers, software-pipelined loads ------
// KSPLIT=14. Per wave: 16 output cols (own C rows), B ring depth 5, A ring depth 8.
__global__ __launch_bounds__(256, 2) void gemm_reg(
    const short* __restrict__ Ap,
    const float* __restrict__ Cre, const float* __restrict__ Cim,
    short* __restrict__ part_all)
{
    constexpr int KSPLIT = 14;
    constexpr int KBLK = KK_ / KSPLIT;  // 1024
    constexpr int NCH  = KBLK / 32;     // 32
    constexpr int BD   = 5;             // B ring depth (chunks)
    constexpr int AD   = 8;             // A ring depth (chunks)

    const int etile = blockIdx.x;       // 0..111
    const int ks    = blockIdx.y;       // 0..13
    const int tid   = threadIdx.x;
    const int wave  = tid >> 6;
    const int lane  = tid & 63;
    const int l16   = lane & 15;
    const int kg    = lane >> 4;

    const float* Cp = (ks < 7) ? Cre : Cim;
    const int kc = (ks % 7) * KBLK;     // col base within C half
    const int ka = ks * KBLK;           // k base in packed A'

    const int e_lane = etile * BE + wave * 16 + l16;     // output col = C row
    const float* crow = Cp + (size_t)e_lane * D_ + kc + kg * 8;
    const short* abase = Ap + (((size_t)(ka >> 3) + kg) * 64 + l16) * 8;

    f32x4  breg[BD][2];
    bf16x8 areg[AD][4];

    // prologue: A chunks 0..7, B chunks 0..4
    #pragma unroll
    for (int j = 0; j < AD; ++j)
        #pragma unroll
        for (int mt = 0; mt < 4; ++mt)
            areg[j][mt] = *reinterpret_cast<const bf16x8*>(abase + (size_t)j * 2048 + mt * 128);
    #pragma unroll
    for (int j = 0; j < BD; ++j) {
        breg[j][0] = *reinterpret_cast<const f32x4*>(crow + j * 32);
        breg[j][1] = *reinterpret_cast<const f32x4*>(crow + j * 32 + 4);
    }
    __builtin_amdgcn_sched_barrier(0);

    f32x4 acc0 = {0.f,0.f,0.f,0.f}, acc1 = {0.f,0.f,0.f,0.f};
    f32x4 acc2 = {0.f,0.f,0.f,0.f}, acc3 = {0.f,0.f,0.f,0.f};

    #pragma unroll
    for (int c = 0; c < NCH; ++c) {
        // consume current B/A (SSA locals keep old values live across the refills)
        f32x4 b0 = breg[c % BD][0];
        f32x4 b1 = breg[c % BD][1];
        bf16x8 a0 = areg[c % AD][0];
        bf16x8 a1 = areg[c % AD][1];
        bf16x8 a2 = areg[c % AD][2];
        bf16x8 a3 = areg[c % AD][3];
        // refill rings (issue early; backend emits counted vmcnt automatically)
        if (c + BD < NCH) {
            breg[c % BD][0] = *reinterpret_cast<const f32x4*>(crow + (c + BD) * 32);
            breg[c % BD][1] = *reinterpret_cast<const f32x4*>(crow + (c + BD) * 32 + 4);
        }
        if (c + AD < NCH) {
            #pragma unroll
            for (int mt = 0; mt < 4; ++mt)
                areg[c % AD][mt] = *reinterpret_cast<const bf16x8*>(
                    abase + (size_t)(c + AD) * 2048 + mt * 128);
        }
        __builtin_amdgcn_sched_barrier(0);
        bf16x8 bfv;
        bfv[0] = f2bf(b0.x); bfv[1] = f2bf(b0.y); bfv[2] = f2bf(b0.z); bfv[3] = f2bf(b0.w);
        bfv[4] = f2bf(b1.x); bfv[5] = f2bf(b1.y); bfv[6] = f2bf(b1.z); bfv[7] = f2bf(b1.w);
        acc0 = __builtin_amdgcn_mfma_f32_16x16x32_bf16(a0, bfv, acc0, 0, 0, 0);
        acc1 = __builtin_amdgcn_mfma_f32_16x16x32_bf16(a1, bfv, acc1, 0, 0, 0);
        acc2 = __builtin_amdgcn_mfma_f32_16x16x32_bf16(a2, bfv, acc2, 0, 0, 0);
        acc3 = __builtin_amdgcn_mfma_f32_16x16x32_bf16(a3, bfv, acc3, 0, 0, 0);
    }

    short* part = part_all + (size_t)ks * (64 * D_);
    #pragma unroll
    for (int mt = 0; mt < 4; ++mt) {
        f32x4 a = (mt == 0) ? acc0 : (mt == 1) ? acc1 : (mt == 2) ? acc2 : acc3;
        int rbase = mt * 16 + kg * 4;       // D-frag: row=(lane>>4)*4+reg, col=lane&15
        #pragma unroll
        for (int r = 0; r < 4; ++r)
            part[(size_t)(rbase + r) * D_ + e_lane] = f2bf(a[r]);
    }
}

// Sum 14 bf16 partials; write the FULL output grid (zeros at non-sc freqs).
__global__ void reduce_full(const short* __restrict__ part, const int* __restrict__ inv,
                            float* __restrict__ out) {
    int t = blockIdx.x * blockDim.x + threadIdx.x;  // 896 rows * 128 f-groups
    if (t >= 896 * 128) return;
    int fg  = t % 128;
    int row = t / 128;          // row = rm*14 + s, rm in [0,64)
    int s   = row % S_;
    int rm  = row / S_;
    int f0  = fg * 8;
    int nn[8];
    #pragma unroll
    for (int j = 0; j < 8; ++j) nn[j] = inv[f0 + j];
    float v[8] = {0.f,0.f,0.f,0.f,0.f,0.f,0.f,0.f};
    #pragma unroll
    for (int ksp = 0; ksp < 14; ++ksp) {
        const short* p = part + ((size_t)ksp * 64 + rm) * D_ + s * 512;
        #pragma unroll
        for (int j = 0; j < 8; ++j)
            if (nn[j] >= 0) v[j] += bf2f(p[nn[j]]);
    }
    float* ob = &out[(size_t)row * F_ + f0];
    #pragma unroll
    for (int j = 0; j < 8; ++j) ob[j] = v[j];
}

// ---------------- fallback (sync, atomic, for small workspace) ----------------
template<int KSPLIT>
__global__ __launch_bounds__(256) void gemm_sync(
    const short* __restrict__ Ap,
    const float* __restrict__ Cre, const float* __restrict__ Cim,
    const int* __restrict__ sc,
    float* __restrict__ out)
{
    constexpr int KBLK = KK_ / KSPLIT;
    constexpr int NCH  = KBLK / 32;
    __shared__ float Bls[3][64 * 32];
    __shared__ short Als[3][64 * 32];

    const int etile = blockIdx.x;
    const int ks    = blockIdx.y;
    const int tid   = threadIdx.x;
    const int wave  = tid >> 6;
    const int lane  = tid & 63;
    const int l16   = lane & 15;
    const int kg    = lane >> 4;

    const float* Cp = (ks < KSPLIT / 2) ? Cre : Cim;
    const int kc = (ks % (KSPLIT / 2)) * KBLK;
    const int ka = ks * KBLK;

    const float* bsrc[2];
    #pragma unroll
    for (int q = 0; q < 2; ++q) {
        int U = q * 256 + tid;
        int row = U >> 3;
        int u = (U & 7) ^ (row & 7);
        bsrc[q] = Cp + (size_t)(etile * BE + row) * D_ + kc + u * 4;
    }
    const short* asrc = Ap + ((size_t)(ka >> 3) * 64) * 8 + tid * 8;

#define STG(c) do { \
        int bf_ = (c) % 3; \
        __builtin_amdgcn_global_load_lds(GLBP(bsrc[0] + (size_t)(c) * 32), \
                                         LDSP(&Bls[bf_][(0 * 256 + tid) * 4]), 16, 0, 0); \
        __builtin_amdgcn_global_load_lds(GLBP(bsrc[1] + (size_t)(c) * 32), \
                                         LDSP(&Bls[bf_][(1 * 256 + tid) * 4]), 16, 0, 0); \
        __builtin_amdgcn_global_load_lds(GLBP(asrc + (size_t)(c) * 2048), \
                                         LDSP(&Als[bf_][tid * 8]), 16, 0, 0); \
    } while (0)

    STG(0);
    STG(1);

    f32x4 acc0 = {0.f,0.f,0.f,0.f}, acc1 = {0.f,0.f,0.f,0.f};
    f32x4 acc2 = {0.f,0.f,0.f,0.f}, acc3 = {0.f,0.f,0.f,0.f};

    const int row  = wave * 16 + l16;
    const int swz  = row & 7;
    const int boff = row * 32;
    const int u0 = ((kg * 2 + 0) ^ swz) * 4;
    const int u1 = ((kg * 2 + 1) ^ swz) * 4;

    for (int c = 0; c < NCH; ++c) {
        if (c < NCH - 1) asm volatile("s_waitcnt vmcnt(3)" ::: "memory");
        else             asm volatile("s_waitcnt vmcnt(0)" ::: "memory");
        __builtin_amdgcn_sched_barrier(0);
        __builtin_amdgcn_s_barrier();

        const int buf = c % 3;
        f32x4 b0 = *reinterpret_cast<const f32x4*>(&Bls[buf][boff + u0]);
        f32x4 b1 = *reinterpret_cast<const f32x4*>(&Bls[buf][boff + u1]);
        bf16x8 a0 = *reinterpret_cast<const bf16x8*>(&Als[buf][(kg * 64 + 0 * 16 + l16) * 8]);
        bf16x8 a1 = *reinterpret_cast<const bf16x8*>(&Als[buf][(kg * 64 + 1 * 16 + l16) * 8]);
        bf16x8 a2 = *reinterpret_cast<const bf16x8*>(&Als[buf][(kg * 64 + 2 * 16 + l16) * 8]);
        bf16x8 a3 = *reinterpret_cast<const bf16x8*>(&Als[buf][(kg * 64 + 3 * 16 + l16) * 8]);
        asm volatile("s_waitcnt lgkmcnt(0)" ::: "memory");
        __builtin_amdgcn_sched_barrier(0);
        __builtin_amdgcn_s_barrier();

        if (c + 2 < NCH) STG(c + 2);

        bf16x8 bfv;
        bfv[0] = f2bf(b0.x); bfv[1] = f2bf(b0.y); bfv[2] = f2bf(b0.z); bfv[3] = f2bf(b0.w);
        bfv[4] = f2bf(b1.x); bfv[5] = f2bf(b1.y); bfv[6] = f2bf(b1.z); bfv[7] = f2bf(b1.w);
        acc0 = __builtin_amdgcn_mfma_f32_16x16x32_bf16(a0, bfv, acc0, 0, 0, 0);
        acc1 = __builtin_amdgcn_mfma_f32_16x16x32_bf16(a1, bfv, acc1, 0, 0, 0);
        acc2 = __builtin_amdgcn_mfma_f32_16x16x32_bf16(a2, bfv, acc2, 0, 0, 0);
        acc3 = __builtin_amdgcn_mfma_f32_16x16x32_bf16(a3, bfv, acc3, 0, 0, 0);
    }
#undef STG

    const int e_lane = etile * BE + row;
    int s = e_lane >> 9, n = e_lane & 511;
    int f = sc[n];
    #pragma unroll
    for (int mt = 0; mt < 4; ++mt) {
        f32x4 a = (mt == 0) ? acc0 : (mt == 1) ? acc1 : (mt == 2) ? acc2 : acc3;
        int rbase = mt * 16 + kg * 4;
        #pragma unroll
        for (int r = 0; r < 4; ++r) {
            int rr = rbase + r;
            int pp = rr >> 5, m = rr & 31;
            atomicAdd(&out[((pp * M_ + m) * S_ + s) * F_ + f], a[r]);
        }
    }
}

extern "C" void kernel_launch(void* const* d_in, const int* in_sizes, int n_in,
                              void* d_out, int out_size, void* d_ws, size_t ws_size,
                              hipStream_t stream) {
    const float* xr  = (const float*)d_in[0];
    const float* xi  = (const float*)d_in[1];
    const float* Cre = (const float*)d_in[2];
    const float* Cim = (const float*)d_in[3];
    const int*   sc  = (const int*)d_in[4];
    float* out = (float*)d_out;

    short* Ap = (short*)d_ws;
    const size_t invOff  = 2u * 1024u * 1024u;
    const size_t partOff = invOff + 4096;
    const size_t partBytes = 14ull * 64 * D_ * 2;      // 12.85 MB
    const bool ok = ws_size >= partOff + partBytes;

    prep_kernel<<<dim3((32 * D_ + 255) / 256), 256, 0, stream>>>(xr, xi, sc, Ap);

    if (ok) {
        int* inv = (int*)((char*)d_ws + invOff);
        short* part = (short*)((char*)d_ws + partOff);
        inv_kernel<<<1, 1024, 0, stream>>>(sc, inv);
        gemm_reg<<<dim3(ETILES, 14), 256, 0, stream>>>(Ap, Cre, Cim, part);
        reduce_full<<<dim3((896 * 128 + 255) / 256), 256, 0, stream>>>(part, inv, out);
    } else {
        zero_kernel<<<dim3((917504 / 4 + 255) / 256), 256, 0, stream>>>((float4*)out, 917504 / 4);
        gemm_sync<16><<<dim3(ETILES, 16), 256, 0, stream>>>(Ap, Cre, Cim, sc, out);
    }
}

// Round 9
// 134.435 us; speedup vs baseline: 1.1166x; 1.1166x over previous
//
#include <hip/hip_runtime.h>
#include <hip/hip_bf16.h>

#define B_ 2
#define R_ 1
#define A_ 16
#define S_ 14
#define F_ 1024
#define N_ 512
#define D_ (S_*N_)        // 7168
#define M_ (B_*R_*A_)     // 32
#define KK_ (2*D_)        // 14336
#define BE 64
#define ETILES (D_/BE)    // 112

typedef __attribute__((ext_vector_type(8))) short bf16x8;
typedef __attribute__((ext_vector_type(4))) float f32x4;

static __device__ inline short f2bf(float f) {
    __hip_bfloat16 h = __float2bfloat16(f);
    return *reinterpret_cast<short*>(&h);
}
static __device__ inline float bf2f(short s) {
    unsigned int u = ((unsigned int)(unsigned short)s) << 16;
    return __uint_as_float(u);
}

#define LDSP(p) ((__attribute__((address_space(3))) void*)(p))
#define GLBP(p) ((const __attribute__((address_space(1))) void*)(p))

// Build packed A' in 16B-unit-transposed layout: Ap[(g*64 + r)*8 + (k&7)], g=k/8.
// rows 0..31: [yr|yi], rows 32..63: [yi|-yr]. One thread per (m,d): 2 reads, 4 writes.
__global__ void prep_kernel(const float* __restrict__ xr, const float* __restrict__ xi,
                            const int* __restrict__ sc, short* __restrict__ Ap) {
    int idx = blockIdx.x * blockDim.x + threadIdx.x;
    if (idx >= 32 * D_) return;
    int d = idx % D_;
    int m = idx / D_;
    int s = d >> 9;
    int n = d & 511;
    int f = sc[n];
    float vr = xr[(m * S_ + s) * F_ + f];
    float vi = xi[(m * S_ + s) * F_ + f];
    int g1 = d >> 3, j = d & 7;
    int g2 = (D_ + d) >> 3;
    Ap[((size_t)g1 * 64 + m) * 8 + j]      = f2bf(vr);
    Ap[((size_t)g1 * 64 + 32 + m) * 8 + j] = f2bf(vi);
    Ap[((size_t)g2 * 64 + m) * 8 + j]      = f2bf(vi);
    Ap[((size_t)g2 * 64 + 32 + m) * 8 + j] = f2bf(-vr);
}

// inv[f] = n if sc[n]==f else -1  (single block)
__global__ void inv_kernel(const int* __restrict__ sc, int* __restrict__ inv) {
    int t = threadIdx.x;
    inv[t] = -1;
    __syncthreads();
    if (t < N_) inv[sc[t]] = t;
}

__global__ void zero_kernel(float4* __restrict__ out, int n4) {
    int i = blockIdx.x * blockDim.x + threadIdx.x;
    if (i < n4) out[i] = make_float4(0.f, 0.f, 0.f, 0.f);
}

// -------- 64k-chunk GEMM: R4 protocol (3-buf, distance-2, counted vmcnt+barriers),
// chunk = 64 rows x 64 k. B swizzled by u^(row&15); A [g][64][8] linear.
__global__ __launch_bounds__(256, 2) void gemm_w64(
    const short* __restrict__ Ap,
    const float* __restrict__ Cre, const float* __restrict__ Cim,
    short* __restrict__ part_all)
{
    constexpr int KSPLIT = 28;
    constexpr int KBLK = KK_ / KSPLIT;  // 512
    constexpr int NCH  = KBLK / 64;     // 8 chunks of 64 k
    __shared__ float Bl[3][64 * 64];    // 16 KB/buf: B tile, 4-bit XOR swizzle
    __shared__ short Al[3][8 * 64 * 8]; // 8 KB/buf: A chunk [g_local][row][8]

    const int etile = blockIdx.x;
    const int ks    = blockIdx.y;
    const int tid   = threadIdx.x;
    const int wave  = tid >> 6;
    const int lane  = tid & 63;
    const int l16   = lane & 15;
    const int kg    = lane >> 4;

    const float* Cp = (ks < 14) ? Cre : Cim;
    const int kc = (ks % 14) * KBLK;    // col base within C half
    const int ka = ks * KBLK;           // k base in packed A'

    // B staging: 4 x 16B units per thread. Unit U = q*256+tid -> row = U>>4,
    // stored slot u' = U&15, source unit u = u' ^ (row&15).
    const float* bsrc[4];
    #pragma unroll
    for (int q = 0; q < 4; ++q) {
        int U = q * 256 + tid;
        int row = U >> 4;
        int us = (U & 15) ^ (row & 15);
        bsrc[q] = Cp + (size_t)(etile * BE + row) * D_ + kc + us * 4;
    }
    // A staging: chunk c = 4096 contiguous shorts at (ka/8 + c*8)*512
    const short* asrcB = Ap + (size_t)(ka >> 3) * 512;

#define STAGE(c) do { \
        int bb = (c) % 3; \
        __builtin_amdgcn_global_load_lds(GLBP(bsrc[0] + (size_t)(c) * 64), \
                                         LDSP(&Bl[bb][(0 * 256 + tid) * 4]), 16, 0, 0); \
        __builtin_amdgcn_global_load_lds(GLBP(bsrc[1] + (size_t)(c) * 64), \
                                         LDSP(&Bl[bb][(1 * 256 + tid) * 4]), 16, 0, 0); \
        __builtin_amdgcn_global_load_lds(GLBP(bsrc[2] + (size_t)(c) * 64), \
                                         LDSP(&Bl[bb][(2 * 256 + tid) * 4]), 16, 0, 0); \
        __builtin_amdgcn_global_load_lds(GLBP(bsrc[3] + (size_t)(c) * 64), \
                                         LDSP(&Bl[bb][(3 * 256 + tid) * 4]), 16, 0, 0); \
        __builtin_amdgcn_global_load_lds(GLBP(asrcB + (size_t)(c) * 4096 + tid * 8), \
                                         LDSP(&Al[bb][tid * 8]), 16, 0, 0); \
        __builtin_amdgcn_global_load_lds(GLBP(asrcB + (size_t)(c) * 4096 + 2048 + tid * 8), \
                                         LDSP(&Al[bb][2048 + tid * 8]), 16, 0, 0); \
    } while (0)

    STAGE(0);
    STAGE(1);

    f32x4 acc0 = {0.f,0.f,0.f,0.f}, acc1 = {0.f,0.f,0.f,0.f};
    f32x4 acc2 = {0.f,0.f,0.f,0.f}, acc3 = {0.f,0.f,0.f,0.f};

    const int row = wave * 16 + l16;    // e within block tile
    const int rx  = row & 15;
    const int rb  = row * 64;

    for (int c = 0; c < NCH; ++c) {
        if (c < NCH - 1) asm volatile("s_waitcnt vmcnt(6)" ::: "memory");
        else             asm volatile("s_waitcnt vmcnt(0)" ::: "memory");
        __builtin_amdgcn_sched_barrier(0);
        __builtin_amdgcn_s_barrier();      // chunk c resident in LDS

        const int buf = c % 3;
        // ds-load both 32-k steps of chunk c (12 x b128)
        f32x4 b00 = *reinterpret_cast<const f32x4*>(&Bl[buf][rb + ((0*8 + kg*2 + 0) ^ rx) * 4]);
        f32x4 b01 = *reinterpret_cast<const f32x4*>(&Bl[buf][rb + ((0*8 + kg*2 + 1) ^ rx) * 4]);
        f32x4 b10 = *reinterpret_cast<const f32x4*>(&Bl[buf][rb + ((1*8 + kg*2 + 0) ^ rx) * 4]);
        f32x4 b11 = *reinterpret_cast<const f32x4*>(&Bl[buf][rb + ((1*8 + kg*2 + 1) ^ rx) * 4]);
        bf16x8 a00 = *reinterpret_cast<const bf16x8*>(&Al[buf][((0*4 + kg) * 64 + 0*16 + l16) * 8]);
        bf16x8 a01 = *reinterpret_cast<const bf16x8*>(&Al[buf][((0*4 + kg) * 64 + 1*16 + l16) * 8]);
        bf16x8 a02 = *reinterpret_cast<const bf16x8*>(&Al[buf][((0*4 + kg) * 64 + 2*16 + l16) * 8]);
        bf16x8 a03 = *reinterpret_cast<const bf16x8*>(&Al[buf][((0*4 + kg) * 64 + 3*16 + l16) * 8]);
        bf16x8 a10 = *reinterpret_cast<const bf16x8*>(&Al[buf][((1*4 + kg) * 64 + 0*16 + l16) * 8]);
        bf16x8 a11 = *reinterpret_cast<const bf16x8*>(&Al[buf][((1*4 + kg) * 64 + 1*16 + l16) * 8]);
        bf16x8 a12 = *reinterpret_cast<const bf16x8*>(&Al[buf][((1*4 + kg) * 64 + 2*16 + l16) * 8]);
        bf16x8 a13 = *reinterpret_cast<const bf16x8*>(&Al[buf][((1*4 + kg) * 64 + 3*16 + l16) * 8]);
        asm volatile("s_waitcnt lgkmcnt(0)" ::: "memory");
        __builtin_amdgcn_sched_barrier(0);
        __builtin_amdgcn_s_barrier();      // all waves done reading buf c%3

        if (c + 2 < NCH) STAGE(c + 2);     // overwrites (c+2)%3 == (c-1)%3 (safe)
        __builtin_amdgcn_sched_barrier(0);

        bf16x8 bv0, bv1;
        bv0[0] = f2bf(b00.x); bv0[1] = f2bf(b00.y); bv0[2] = f2bf(b00.z); bv0[3] = f2bf(b00.w);
        bv0[4] = f2bf(b01.x); bv0[5] = f2bf(b01.y); bv0[6] = f2bf(b01.z); bv0[7] = f2bf(b01.w);
        bv1[0] = f2bf(b10.x); bv1[1] = f2bf(b10.y); bv1[2] = f2bf(b10.z); bv1[3] = f2bf(b10.w);
        bv1[4] = f2bf(b11.x); bv1[5] = f2bf(b11.y); bv1[6] = f2bf(b11.z); bv1[7] = f2bf(b11.w);
        acc0 = __builtin_amdgcn_mfma_f32_16x16x32_bf16(a00, bv0, acc0, 0, 0, 0);
        acc1 = __builtin_amdgcn_mfma_f32_16x16x32_bf16(a01, bv0, acc1, 0, 0, 0);
        acc2 = __builtin_amdgcn_mfma_f32_16x16x32_bf16(a02, bv0, acc2, 0, 0, 0);
        acc3 = __builtin_amdgcn_mfma_f32_16x16x32_bf16(a03, bv0, acc3, 0, 0, 0);
        acc0 = __builtin_amdgcn_mfma_f32_16x16x32_bf16(a10, bv1, acc0, 0, 0, 0);
        acc1 = __builtin_amdgcn_mfma_f32_16x16x32_bf16(a11, bv1, acc1, 0, 0, 0);
        acc2 = __builtin_amdgcn_mfma_f32_16x16x32_bf16(a12, bv1, acc2, 0, 0, 0);
        acc3 = __builtin_amdgcn_mfma_f32_16x16x32_bf16(a13, bv1, acc3, 0, 0, 0);
    }
#undef STAGE

    const int e_lane = etile * BE + row;
    short* part = part_all + (size_t)ks * (64 * D_);
    #pragma unroll
    for (int mt = 0; mt < 4; ++mt) {
        f32x4 a = (mt == 0) ? acc0 : (mt == 1) ? acc1 : (mt == 2) ? acc2 : acc3;
        int rbase = mt * 16 + kg * 4;       // D-frag: row=(lane>>4)*4+reg, col=lane&15
        #pragma unroll
        for (int r = 0; r < 4; ++r)
            part[(size_t)(rbase + r) * D_ + e_lane] = f2bf(a[r]);
    }
}

// Sum 28 bf16 partials; write the FULL output grid (zeros at non-sc freqs).
__global__ void reduce_full(const short* __restrict__ part, const int* __restrict__ inv,
                            float* __restrict__ out) {
    int t = blockIdx.x * blockDim.x + threadIdx.x;  // 896 rows * 128 f-groups
    if (t >= 896 * 128) return;
    int fg  = t % 128;
    int row = t / 128;          // row = rm*14 + s, rm in [0,64)
    int s   = row % S_;
    int rm  = row / S_;
    int f0  = fg * 8;
    int nn[8];
    #pragma unroll
    for (int j = 0; j < 8; ++j) nn[j] = inv[f0 + j];
    float v[8] = {0.f,0.f,0.f,0.f,0.f,0.f,0.f,0.f};
    #pragma unroll
    for (int ksp = 0; ksp < 28; ++ksp) {
        const short* p = part + ((size_t)ksp * 64 + rm) * D_ + s * 512;
        #pragma unroll
        for (int j = 0; j < 8; ++j)
            if (nn[j] >= 0) v[j] += bf2f(p[nn[j]]);
    }
    float* ob = &out[(size_t)row * F_ + f0];
    #pragma unroll
    for (int j = 0; j < 8; ++j) ob[j] = v[j];
}

// ---------------- fallback (sync, atomic, for small workspace) ----------------
template<int KSPLIT>
__global__ __launch_bounds__(256) void gemm_sync(
    const short* __restrict__ Ap,
    const float* __restrict__ Cre, const float* __restrict__ Cim,
    const int* __restrict__ sc,
    float* __restrict__ out)
{
    constexpr int KBLK = KK_ / KSPLIT;
    constexpr int NCH  = KBLK / 32;
    __shared__ float Bls[3][64 * 32];
    __shared__ short Als[3][64 * 32];

    const int etile = blockIdx.x;
    const int ks    = blockIdx.y;
    const int tid   = threadIdx.x;
    const int wave  = tid >> 6;
    const int lane  = tid & 63;
    const int l16   = lane & 15;
    const int kg    = lane >> 4;

    const float* Cp = (ks < KSPLIT / 2) ? Cre : Cim;
    const int kc = (ks % (KSPLIT / 2)) * KBLK;
    const int ka = ks * KBLK;

    const float* bsrc[2];
    #pragma unroll
    for (int q = 0; q < 2; ++q) {
        int U = q * 256 + tid;
        int row = U >> 3;
        int u = (U & 7) ^ (row & 7);
        bsrc[q] = Cp + (size_t)(etile * BE + row) * D_ + kc + u * 4;
    }
    const short* asrc = Ap + ((size_t)(ka >> 3) * 64) * 8 + tid * 8;

#define STG(c) do { \
        int bf_ = (c) % 3; \
        __builtin_amdgcn_global_load_lds(GLBP(bsrc[0] + (size_t)(c) * 32), \
                                         LDSP(&Bls[bf_][(0 * 256 + tid) * 4]), 16, 0, 0); \
        __builtin_amdgcn_global_load_lds(GLBP(bsrc[1] + (size_t)(c) * 32), \
                                         LDSP(&Bls[bf_][(1 * 256 + tid) * 4]), 16, 0, 0); \
        __builtin_amdgcn_global_load_lds(GLBP(asrc + (size_t)(c) * 2048), \
                                         LDSP(&Als[bf_][tid * 8]), 16, 0, 0); \
    } while (0)

    STG(0);
    STG(1);

    f32x4 acc0 = {0.f,0.f,0.f,0.f}, acc1 = {0.f,0.f,0.f,0.f};
    f32x4 acc2 = {0.f,0.f,0.f,0.f}, acc3 = {0.f,0.f,0.f,0.f};

    const int row  = wave * 16 + l16;
    const int swz  = row & 7;
    const int boff = row * 32;
    const int u0 = ((kg * 2 + 0) ^ swz) * 4;
    const int u1 = ((kg * 2 + 1) ^ swz) * 4;

    for (int c = 0; c < NCH; ++c) {
        if (c < NCH - 1) asm volatile("s_waitcnt vmcnt(3)" ::: "memory");
        else             asm volatile("s_waitcnt vmcnt(0)" ::: "memory");
        __builtin_amdgcn_sched_barrier(0);
        __builtin_amdgcn_s_barrier();

        const int buf = c % 3;
        f32x4 b0 = *reinterpret_cast<const f32x4*>(&Bls[buf][boff + u0]);
        f32x4 b1 = *reinterpret_cast<const f32x4*>(&Bls[buf][boff + u1]);
        bf16x8 a0 = *reinterpret_cast<const bf16x8*>(&Als[buf][(kg * 64 + 0 * 16 + l16) * 8]);
        bf16x8 a1 = *reinterpret_cast<const bf16x8*>(&Als[buf][(kg * 64 + 1 * 16 + l16) * 8]);
        bf16x8 a2 = *reinterpret_cast<const bf16x8*>(&Als[buf][(kg * 64 + 2 * 16 + l16) * 8]);
        bf16x8 a3 = *reinterpret_cast<const bf16x8*>(&Als[buf][(kg * 64 + 3 * 16 + l16) * 8]);
        asm volatile("s_waitcnt lgkmcnt(0)" ::: "memory");
        __builtin_amdgcn_sched_barrier(0);
        __builtin_amdgcn_s_barrier();

        if (c + 2 < NCH) STG(c + 2);

        bf16x8 bfv;
        bfv[0] = f2bf(b0.x); bfv[1] = f2bf(b0.y); bfv[2] = f2bf(b0.z); bfv[3] = f2bf(b0.w);
        bfv[4] = f2bf(b1.x); bfv[5] = f2bf(b1.y); bfv[6] = f2bf(b1.z); bfv[7] = f2bf(b1.w);
        acc0 = __builtin_amdgcn_mfma_f32_16x16x32_bf16(a0, bfv, acc0, 0, 0, 0);
        acc1 = __builtin_amdgcn_mfma_f32_16x16x32_bf16(a1, bfv, acc1, 0, 0, 0);
        acc2 = __builtin_amdgcn_mfma_f32_16x16x32_bf16(a2, bfv, acc2, 0, 0, 0);
        acc3 = __builtin_amdgcn_mfma_f32_16x16x32_bf16(a3, bfv, acc3, 0, 0, 0);
    }
#undef STG

    const int e_lane = etile * BE + row;
    int s = e_lane >> 9, n = e_lane & 511;
    int f = sc[n];
    #pragma unroll
    for (int mt = 0; mt < 4; ++mt) {
        f32x4 a = (mt == 0) ? acc0 : (mt == 1) ? acc1 : (mt == 2) ? acc2 : acc3;
        int rbase = mt * 16 + kg * 4;
        #pragma unroll
        for (int r = 0; r < 4; ++r) {
            int rr = rbase + r;
            int pp = rr >> 5, m = rr & 31;
            atomicAdd(&out[((pp * M_ + m) * S_ + s) * F_ + f], a[r]);
        }
    }
}

extern "C" void kernel_launch(void* const* d_in, const int* in_sizes, int n_in,
                              void* d_out, int out_size, void* d_ws, size_t ws_size,
                              hipStream_t stream) {
    const float* xr  = (const float*)d_in[0];
    const float* xi  = (const float*)d_in[1];
    const float* Cre = (const float*)d_in[2];
    const float* Cim = (const float*)d_in[3];
    const int*   sc  = (const int*)d_in[4];
    float* out = (float*)d_out;

    short* Ap = (short*)d_ws;
    const size_t invOff  = 2u * 1024u * 1024u;
    const size_t partOff = invOff + 4096;
    const size_t partBytes = 28ull * 64 * D_ * 2;      // 25.7 MB
    const bool ok = ws_size >= partOff + partBytes;

    prep_kernel<<<dim3((32 * D_ + 255) / 256), 256, 0, stream>>>(xr, xi, sc, Ap);

    if (ok) {
        int* inv = (int*)((char*)d_ws + invOff);
        short* part = (short*)((char*)d_ws + partOff);
        inv_kernel<<<1, 1024, 0, stream>>>(sc, inv);
        gemm_w64<<<dim3(ETILES, 28), 256, 0, stream>>>(Ap, Cre, Cim, part);
        reduce_full<<<dim3((896 * 128 + 255) / 256), 256, 0, stream>>>(part, inv, out);
    } else {
        zero_kernel<<<dim3((917504 / 4 + 255) / 256), 256, 0, stream>>>((float4*)out, 917504 / 4);
        gemm_sync<16><<<dim3(ETILES, 16), 256, 0, stream>>>(Ap, Cre, Cim, sc, out);
    }
}

// Round 11
// 134.218 us; speedup vs baseline: 1.1184x; 1.0016x over previous
//
#include <hip/hip_runtime.h>
#include <hip/hip_bf16.h>

#define B_ 2
#define R_ 1
#define A_ 16
#define S_ 14
#define F_ 1024
#define N_ 512
#define D_ (S_*N_)        // 7168
#define M_ (B_*R_*A_)     // 32
#define KK_ (2*D_)        // 14336
#define BE 64

typedef __attribute__((ext_vector_type(8))) short bf16x8;
typedef __attribute__((ext_vector_type(4))) float f32x4;

static __device__ inline short f2bf(float f) {
    __hip_bfloat16 h = __float2bfloat16(f);
    return *reinterpret_cast<short*>(&h);
}
static __device__ inline float bf2f(short s) {
    unsigned int u = ((unsigned int)(unsigned short)s) << 16;
    return __uint_as_float(u);
}

#define LDSP(p) ((__attribute__((address_space(3))) void*)(p))
#define GLBP(p) ((const __attribute__((address_space(1))) void*)(p))

// Build packed A' in 16B-unit-transposed layout: Ap[(g*64 + r)*8 + (k&7)], g=k/8.
// rows 0..31: [yr|yi], rows 32..63: [yi|-yr]. One thread per (m,d): 2 reads, 4 writes.
__global__ void prep_kernel(const float* __restrict__ xr, const float* __restrict__ xi,
                            const int* __restrict__ sc, short* __restrict__ Ap) {
    int idx = blockIdx.x * blockDim.x + threadIdx.x;
    if (idx >= 32 * D_) return;
    int d = idx % D_;
    int m = idx / D_;
    int s = d >> 9;
    int n = d & 511;
    int f = sc[n];
    float vr = xr[(m * S_ + s) * F_ + f];
    float vi = xi[(m * S_ + s) * F_ + f];
    int g1 = d >> 3, j = d & 7;
    int g2 = (D_ + d) >> 3;
    Ap[((size_t)g1 * 64 + m) * 8 + j]      = f2bf(vr);
    Ap[((size_t)g1 * 64 + 32 + m) * 8 + j] = f2bf(vi);
    Ap[((size_t)g2 * 64 + m) * 8 + j]      = f2bf(vi);
    Ap[((size_t)g2 * 64 + 32 + m) * 8 + j] = f2bf(-vr);
}

// inv[f] = n if sc[n]==f else -1  (single block)
__global__ void inv_kernel(const int* __restrict__ sc, int* __restrict__ inv) {
    int t = threadIdx.x;
    inv[t] = -1;
    __syncthreads();
    if (t < N_) inv[sc[t]] = t;
}

__global__ void zero_kernel(float4* __restrict__ out, int n4) {
    int i = blockIdx.x * blockDim.x + threadIdx.x;
    if (i < n4) out[i] = make_float4(0.f, 0.f, 0.f, 0.f);
}

// ------- BE=128 GEMM: R4 protocol (32k chunks, 3-buf, dist-2, counted vmcnt),
// 512 threads / 8 waves. Waves 0-3 stage A too (3 ops/chunk), waves 4-7 B only
// (2 ops/chunk). Wait rule: outstanding = 2 chunks at loop top -> wait
// vmcnt(ops_per_chunk) (3 / 2); last iter: 1 chunk outstanding -> vmcnt(0).
__global__ __launch_bounds__(512, 4) void gemm_w128(
    const short* __restrict__ Ap,
    const float* __restrict__ Cre, const float* __restrict__ Cim,
    short* __restrict__ part_all)
{
    constexpr int KSPLIT = 28;
    constexpr int KBLK = KK_ / KSPLIT;  // 512
    constexpr int NCH  = KBLK / 32;     // 16
    __shared__ float Bl[3][128 * 32];   // 16 KB/buf, XOR-swizzled C tile (f32)
    __shared__ short Al[3][4 * 64 * 8]; // 4 KB/buf, [g_local][row][8] A' chunk

    const int etile = blockIdx.x;       // 0..55
    const int ks    = blockIdx.y;       // 0..27
    const int tid   = threadIdx.x;      // 0..511
    const int wave  = tid >> 6;
    const int lane  = tid & 63;
    const int l16   = lane & 15;
    const int kg    = lane >> 4;
    const bool waveA = (tid < 256);     // waves 0-3 stage A too (wave-uniform)

    const float* Cp = (ks < 14) ? Cre : Cim;
    const int kc = (ks % 14) * KBLK;    // col base within C half
    const int ka = ks * KBLK;           // k base in packed A'

    // B staging sources: 2 x 16B units per thread. Unit U = q*512 + tid ->
    // row = U>>3 (0..127), stored slot u' = U&7, source unit u = u' ^ (row&7).
    const int U0 = tid, U1 = 512 + tid;
    const float* bsrc0 = Cp + (size_t)(etile * 128 + (U0 >> 3)) * D_
                            + kc + ((U0 & 7) ^ ((U0 >> 3) & 7)) * 4;
    const float* bsrc1 = Cp + (size_t)(etile * 128 + (U1 >> 3)) * D_
                            + kc + ((U1 & 7) ^ ((U1 >> 3) & 7)) * 4;
    // A staging: chunk c = 2048 contiguous shorts at (ka>>3)*512 + c*2048
    const short* asrcB = Ap + (size_t)(ka >> 3) * 512;

#define WAITV(n) asm volatile("s_waitcnt vmcnt(" #n ")" ::: "memory")
#define STAGE(c) do { \
        int bb = (c) % 3; \
        __builtin_amdgcn_global_load_lds(GLBP(bsrc0 + (size_t)(c) * 32), \
                                         LDSP(&Bl[bb][U0 * 4]), 16, 0, 0); \
        __builtin_amdgcn_global_load_lds(GLBP(bsrc1 + (size_t)(c) * 32), \
                                         LDSP(&Bl[bb][U1 * 4]), 16, 0, 0); \
        if (waveA) \
            __builtin_amdgcn_global_load_lds(GLBP(asrcB + (size_t)(c) * 2048 + tid * 8), \
                                             LDSP(&Al[bb][tid * 8]), 16, 0, 0); \
    } while (0)

    STAGE(0);
    STAGE(1);

    f32x4 acc0 = {0.f,0.f,0.f,0.f}, acc1 = {0.f,0.f,0.f,0.f};
    f32x4 acc2 = {0.f,0.f,0.f,0.f}, acc3 = {0.f,0.f,0.f,0.f};

    const int row_e = wave * 16 + l16;   // e within block tile (0..127)
    const int rx   = row_e & 7;
    const int boff = row_e * 32;
    const int u0x = ((kg * 2 + 0) ^ rx) * 4;
    const int u1x = ((kg * 2 + 1) ^ rx) * 4;

    for (int c = 0; c < NCH; ++c) {
        // chunk-c completion: 2 chunks outstanding until the last iteration
        if (c < NCH - 1) { if (waveA) WAITV(3); else WAITV(2); }
        else             { WAITV(0); }
        __builtin_amdgcn_sched_barrier(0);
        __builtin_amdgcn_s_barrier();      // chunk c resident in LDS

        const int buf = c % 3;
        f32x4 b0 = *reinterpret_cast<const f32x4*>(&Bl[buf][boff + u0x]);
        f32x4 b1 = *reinterpret_cast<const f32x4*>(&Bl[buf][boff + u1x]);
        bf16x8 a0 = *reinterpret_cast<const bf16x8*>(&Al[buf][(kg * 64 + 0 * 16 + l16) * 8]);
        bf16x8 a1 = *reinterpret_cast<const bf16x8*>(&Al[buf][(kg * 64 + 1 * 16 + l16) * 8]);
        bf16x8 a2 = *reinterpret_cast<const bf16x8*>(&Al[buf][(kg * 64 + 2 * 16 + l16) * 8]);
        bf16x8 a3 = *reinterpret_cast<const bf16x8*>(&Al[buf][(kg * 64 + 3 * 16 + l16) * 8]);
        asm volatile("s_waitcnt lgkmcnt(0)" ::: "memory");
        __builtin_amdgcn_sched_barrier(0);
        __builtin_amdgcn_s_barrier();      // all waves done reading buf c%3

        if (c + 2 < NCH) STAGE(c + 2);     // overwrites (c+2)%3 == (c-1)%3 (safe)
        __builtin_amdgcn_sched_barrier(0);

        bf16x8 bfv;
        bfv[0] = f2bf(b0.x); bfv[1] = f2bf(b0.y); bfv[2] = f2bf(b0.z); bfv[3] = f2bf(b0.w);
        bfv[4] = f2bf(b1.x); bfv[5] = f2bf(b1.y); bfv[6] = f2bf(b1.z); bfv[7] = f2bf(b1.w);
        acc0 = __builtin_amdgcn_mfma_f32_16x16x32_bf16(a0, bfv, acc0, 0, 0, 0);
        acc1 = __builtin_amdgcn_mfma_f32_16x16x32_bf16(a1, bfv, acc1, 0, 0, 0);
        acc2 = __builtin_amdgcn_mfma_f32_16x16x32_bf16(a2, bfv, acc2, 0, 0, 0);
        acc3 = __builtin_amdgcn_mfma_f32_16x16x32_bf16(a3, bfv, acc3, 0, 0, 0);
    }
#undef STAGE
#undef WAITV

    const int e_lane = etile * 128 + row_e;
    short* part = part_all + (size_t)ks * (64 * D_);
    #pragma unroll
    for (int mt = 0; mt < 4; ++mt) {
        f32x4 a = (mt == 0) ? acc0 : (mt == 1) ? acc1 : (mt == 2) ? acc2 : acc3;
        int rbase = mt * 16 + kg * 4;       // D-frag: row=(lane>>4)*4+reg, col=lane&15
        #pragma unroll
        for (int r = 0; r < 4; ++r)
            part[(size_t)(rbase + r) * D_ + e_lane] = f2bf(a[r]);
    }
}

// Sum 28 bf16 partials; write the FULL output grid (zeros at non-sc freqs).
__global__ void reduce_full(const short* __restrict__ part, const int* __restrict__ inv,
                            float* __restrict__ out) {
    int t = blockIdx.x * blockDim.x + threadIdx.x;  // 896 rows * 128 f-groups
    if (t >= 896 * 128) return;
    int fg  = t % 128;
    int row = t / 128;          // row = rm*14 + s, rm in [0,64)
    int s   = row % S_;
    int rm  = row / S_;
    int f0  = fg * 8;
    int nn[8];
    #pragma unroll
    for (int j = 0; j < 8; ++j) nn[j] = inv[f0 + j];
    float v[8] = {0.f,0.f,0.f,0.f,0.f,0.f,0.f,0.f};
    #pragma unroll
    for (int ksp = 0; ksp < 28; ++ksp) {
        const short* p = part + ((size_t)ksp * 64 + rm) * D_ + s * 512;
        #pragma unroll
        for (int j = 0; j < 8; ++j)
            if (nn[j] >= 0) v[j] += bf2f(p[nn[j]]);
    }
    float* ob = &out[(size_t)row * F_ + f0];
    #pragma unroll
    for (int j = 0; j < 8; ++j) ob[j] = v[j];
}

// ---------------- fallback (sync, atomic, for small workspace) ----------------
template<int KSPLIT>
__global__ __launch_bounds__(256) void gemm_sync(
    const short* __restrict__ Ap,
    const float* __restrict__ Cre, const float* __restrict__ Cim,
    const int* __restrict__ sc,
    float* __restrict__ out)
{
    constexpr int KBLK = KK_ / KSPLIT;
    constexpr int NCH  = KBLK / 32;
    __shared__ float Bls[3][64 * 32];
    __shared__ short Als[3][64 * 32];

    const int etile = blockIdx.x;
    const int ks    = blockIdx.y;
    const int tid   = threadIdx.x;
    const int wave  = tid >> 6;
    const int lane  = tid & 63;
    const int l16   = lane & 15;
    const int kg    = lane >> 4;

    const float* Cp = (ks < KSPLIT / 2) ? Cre : Cim;
    const int kc = (ks % (KSPLIT / 2)) * KBLK;
    const int ka = ks * KBLK;

    const float* bsrc[2];
    #pragma unroll
    for (int q = 0; q < 2; ++q) {
        int U = q * 256 + tid;
        int row = U >> 3;
        int u = (U & 7) ^ (row & 7);
        bsrc[q] = Cp + (size_t)(etile * BE + row) * D_ + kc + u * 4;
    }
    const short* asrc = Ap + ((size_t)(ka >> 3) * 64) * 8 + tid * 8;

#define STG(c) do { \
        int bf_ = (c) % 3; \
        __builtin_amdgcn_global_load_lds(GLBP(bsrc[0] + (size_t)(c) * 32), \
                                         LDSP(&Bls[bf_][(0 * 256 + tid) * 4]), 16, 0, 0); \
        __builtin_amdgcn_global_load_lds(GLBP(bsrc[1] + (size_t)(c) * 32), \
                                         LDSP(&Bls[bf_][(1 * 256 + tid) * 4]), 16, 0, 0); \
        __builtin_amdgcn_global_load_lds(GLBP(asrc + (size_t)(c) * 2048), \
                                         LDSP(&Als[bf_][tid * 8]), 16, 0, 0); \
    } while (0)

    STG(0);
    STG(1);

    f32x4 acc0 = {0.f,0.f,0.f,0.f}, acc1 = {0.f,0.f,0.f,0.f};
    f32x4 acc2 = {0.f,0.f,0.f,0.f}, acc3 = {0.f,0.f,0.f,0.f};

    const int row  = wave * 16 + l16;
    const int swz  = row & 7;
    const int boff = row * 32;
    const int u0 = ((kg * 2 + 0) ^ swz) * 4;
    const int u1 = ((kg * 2 + 1) ^ swz) * 4;

    for (int c = 0; c < NCH; ++c) {
        if (c < NCH - 1) asm volatile("s_waitcnt vmcnt(3)" ::: "memory");
        else             asm volatile("s_waitcnt vmcnt(0)" ::: "memory");
        __builtin_amdgcn_sched_barrier(0);
        __builtin_amdgcn_s_barrier();

        const int buf = c % 3;
        f32x4 b0 = *reinterpret_cast<const f32x4*>(&Bls[buf][boff + u0]);
        f32x4 b1 = *reinterpret_cast<const f32x4*>(&Bls[buf][boff + u1]);
        bf16x8 a0 = *reinterpret_cast<const bf16x8*>(&Als[buf][(kg * 64 + 0 * 16 + l16) * 8]);
        bf16x8 a1 = *reinterpret_cast<const bf16x8*>(&Als[buf][(kg * 64 + 1 * 16 + l16) * 8]);
        bf16x8 a2 = *reinterpret_cast<const bf16x8*>(&Als[buf][(kg * 64 + 2 * 16 + l16) * 8]);
        bf16x8 a3 = *reinterpret_cast<const bf16x8*>(&Als[buf][(kg * 64 + 3 * 16 + l16) * 8]);
        asm volatile("s_waitcnt lgkmcnt(0)" ::: "memory");
        __builtin_amdgcn_sched_barrier(0);
        __builtin_amdgcn_s_barrier();

        if (c + 2 < NCH) STG(c + 2);

        bf16x8 bfv;
        bfv[0] = f2bf(b0.x); bfv[1] = f2bf(b0.y); bfv[2] = f2bf(b0.z); bfv[3] = f2bf(b0.w);
        bfv[4] = f2bf(b1.x); bfv[5] = f2bf(b1.y); bfv[6] = f2bf(b1.z); bfv[7] = f2bf(b1.w);
        acc0 = __builtin_amdgcn_mfma_f32_16x16x32_bf16(a0, bfv, acc0, 0, 0, 0);
        acc1 = __builtin_amdgcn_mfma_f32_16x16x32_bf16(a1, bfv, acc1, 0, 0, 0);
        acc2 = __builtin_amdgcn_mfma_f32_16x16x32_bf16(a2, bfv, acc2, 0, 0, 0);
        acc3 = __builtin_amdgcn_mfma_f32_16x16x32_bf16(a3, bfv, acc3, 0, 0, 0);
    }
#undef STG

    const int e_lane = etile * BE + row;
    int s = e_lane >> 9, n = e_lane & 511;
    int f = sc[n];
    #pragma unroll
    for (int mt = 0; mt < 4; ++mt) {
        f32x4 a = (mt == 0) ? acc0 : (mt == 1) ? acc1 : (mt == 2) ? acc2 : acc3;
        int rbase = mt * 16 + kg * 4;
        #pragma unroll
        for (int r = 0; r < 4; ++r) {
            int rr = rbase + r;
            int pp = rr >> 5, m = rr & 31;
            atomicAdd(&out[((pp * M_ + m) * S_ + s) * F_ + f], a[r]);
        }
    }
}

extern "C" void kernel_launch(void* const* d_in, const int* in_sizes, int n_in,
                              void* d_out, int out_size, void* d_ws, size_t ws_size,
                              hipStream_t stream) {
    const float* xr  = (const float*)d_in[0];
    const float* xi  = (const float*)d_in[1];
    const float* Cre = (const float*)d_in[2];
    const float* Cim = (const float*)d_in[3];
    const int*   sc  = (const int*)d_in[4];
    float* out = (float*)d_out;

    short* Ap = (short*)d_ws;
    const size_t invOff  = 2u * 1024u * 1024u;
    const size_t partOff = invOff + 4096;
    const size_t partBytes = 28ull * 64 * D_ * 2;      // 25.7 MB
    const bool ok = ws_size >= partOff + partBytes;

    prep_kernel<<<dim3((32 * D_ + 255) / 256), 256, 0, stream>>>(xr, xi, sc, Ap);

    if (ok) {
        int* inv = (int*)((char*)d_ws + invOff);
        short* part = (short*)((char*)d_ws + partOff);
        inv_kernel<<<1, 1024, 0, stream>>>(sc, inv);
        gemm_w128<<<dim3(56, 28), 512, 0, stream>>>(Ap, Cre, Cim, part);
        reduce_full<<<dim3((896 * 128 + 255) / 256), 256, 0, stream>>>(part, inv, out);
    } else {
        zero_kernel<<<dim3((917504 / 4 + 255) / 256), 256, 0, stream>>>((float4*)out, 917504 / 4);
        gemm_sync<16><<<dim3(112, 16), 256, 0, stream>>>(Ap, Cre, Cim, sc, out);
    }
}

// Round 12
// 107.271 us; speedup vs baseline: 1.3993x; 1.2512x over previous
//
#include <hip/hip_runtime.h>
#include <hip/hip_bf16.h>

#define B_ 2
#define R_ 1
#define A_ 16
#define S_ 14
#define F_ 1024
#define N_ 512
#define D_ (S_*N_)        // 7168
#define M_ (B_*R_*A_)     // 32
#define KK_ (2*D_)        // 14336
#define BE 64
#define ETILES (D_/BE)    // 112

typedef __attribute__((ext_vector_type(8))) short bf16x8;
typedef __attribute__((ext_vector_type(4))) float f32x4;

static __device__ inline short f2bf(float f) {
    __hip_bfloat16 h = __float2bfloat16(f);
    return *reinterpret_cast<short*>(&h);
}
static __device__ inline float bf2f(short s) {
    unsigned int u = ((unsigned int)(unsigned short)s) << 16;
    return __uint_as_float(u);
}

#define LDSP(p) ((__attribute__((address_space(3))) void*)(p))
#define GLBP(p) ((const __attribute__((address_space(1))) void*)(p))

// Build packed A' in 16B-unit-transposed layout: Ap[(g*64 + r)*8 + (k&7)], g=k/8.
// rows 0..31: [yr|yi], rows 32..63: [yi|-yr]. One thread per (m,d): 2 reads, 4 writes.
__global__ void prep_kernel(const float* __restrict__ xr, const float* __restrict__ xi,
                            const int* __restrict__ sc, short* __restrict__ Ap) {
    int idx = blockIdx.x * blockDim.x + threadIdx.x;
    if (idx >= 32 * D_) return;
    int d = idx % D_;
    int m = idx / D_;
    int s = d >> 9;
    int n = d & 511;
    int f = sc[n];
    float vr = xr[(m * S_ + s) * F_ + f];
    float vi = xi[(m * S_ + s) * F_ + f];
    int g1 = d >> 3, j = d & 7;
    int g2 = (D_ + d) >> 3;
    Ap[((size_t)g1 * 64 + m) * 8 + j]      = f2bf(vr);
    Ap[((size_t)g1 * 64 + 32 + m) * 8 + j] = f2bf(vi);
    Ap[((size_t)g2 * 64 + m) * 8 + j]      = f2bf(vi);
    Ap[((size_t)g2 * 64 + 32 + m) * 8 + j] = f2bf(-vr);
}

__global__ void zero_kernel(float4* __restrict__ out, int n4) {
    int i = blockIdx.x * blockDim.x + threadIdx.x;
    if (i < n4) out[i] = make_float4(0.f, 0.f, 0.f, 0.f);
}

// ---- R4-champion GEMM, 2-buffer variant: 32k chunks, dist-2 prefetch,
// counted vmcnt + raw barriers. LDS 24 KB -> 6 blocks/CU (24 waves/CU).
// stage(c+2) writes buf c%2, which barrier #2 just certified fully-read;
// chunk c+1 lives in the other buffer, untouched.
template<int KSPLIT, int PARTIALS>
__global__ __launch_bounds__(256, 6) void gemm_kernel(
    const short* __restrict__ Ap,
    const float* __restrict__ Cre, const float* __restrict__ Cim,
    const int* __restrict__ sc,
    void* __restrict__ outp)
{
    constexpr int KBLK = KK_ / KSPLIT;   // 512 (KSPLIT=28)
    constexpr int NCH  = KBLK / 32;      // 16
    __shared__ float Bl[2][64 * 32];     // 8 KB/buf, XOR-swizzled C tile (f32)
    __shared__ short Al[2][64 * 32];     // 4 KB/buf, [g_local][row][8] A' chunk

    const int etile = blockIdx.x;
    const int ks    = blockIdx.y;
    const int tid   = threadIdx.x;
    const int wave  = tid >> 6;
    const int lane  = tid & 63;
    const int l16   = lane & 15;
    const int kg    = lane >> 4;

    const float* Cp = (ks < KSPLIT / 2) ? Cre : Cim;
    const int kc = (ks % (KSPLIT / 2)) * KBLK;   // col base within C half
    const int ka = ks * KBLK;                    // k base in packed A'

    // B staging: 2 x 16B units/thread. Unit U = q*256+tid -> row = U>>3,
    // stored slot u' = U&7, source unit u = u' ^ (row&7)  (XOR involution)
    const float* bsrc[2];
    #pragma unroll
    for (int q = 0; q < 2; ++q) {
        int U = q * 256 + tid;
        int row = U >> 3;
        int u = (U & 7) ^ (row & 7);
        bsrc[q] = Cp + (size_t)(etile * BE + row) * D_ + kc + u * 4;
    }
    // A staging: chunk c = 2048 contiguous shorts (1 x 16B op/thread)
    const short* asrc = Ap + ((size_t)(ka >> 3) * 64) * 8 + tid * 8;

#define STAGE(c) do { \
        int bb = (c) & 1; \
        __builtin_amdgcn_global_load_lds(GLBP(bsrc[0] + (size_t)(c) * 32), \
                                         LDSP(&Bl[bb][(0 * 256 + tid) * 4]), 16, 0, 0); \
        __builtin_amdgcn_global_load_lds(GLBP(bsrc[1] + (size_t)(c) * 32), \
                                         LDSP(&Bl[bb][(1 * 256 + tid) * 4]), 16, 0, 0); \
        __builtin_amdgcn_global_load_lds(GLBP(asrc + (size_t)(c) * 2048), \
                                         LDSP(&Al[bb][tid * 8]), 16, 0, 0); \
    } while (0)

    STAGE(0);
    STAGE(1);

    f32x4 acc0 = {0.f,0.f,0.f,0.f}, acc1 = {0.f,0.f,0.f,0.f};
    f32x4 acc2 = {0.f,0.f,0.f,0.f}, acc3 = {0.f,0.f,0.f,0.f};

    const int row  = wave * 16 + l16;
    const int swz  = row & 7;
    const int boff = row * 32;
    const int u0 = ((kg * 2 + 0) ^ swz) * 4;
    const int u1 = ((kg * 2 + 1) ^ swz) * 4;

    for (int c = 0; c < NCH; ++c) {
        // outstanding at top: chunks c and c+1 (3 ops each); last iter: c only
        if (c < NCH - 1) asm volatile("s_waitcnt vmcnt(3)" ::: "memory");
        else             asm volatile("s_waitcnt vmcnt(0)" ::: "memory");
        __builtin_amdgcn_sched_barrier(0);
        __builtin_amdgcn_s_barrier();      // chunk c resident in LDS

        const int buf = c & 1;
        f32x4 b0 = *reinterpret_cast<const f32x4*>(&Bl[buf][boff + u0]);
        f32x4 b1 = *reinterpret_cast<const f32x4*>(&Bl[buf][boff + u1]);
        bf16x8 a0 = *reinterpret_cast<const bf16x8*>(&Al[buf][(kg * 64 + 0 * 16 + l16) * 8]);
        bf16x8 a1 = *reinterpret_cast<const bf16x8*>(&Al[buf][(kg * 64 + 1 * 16 + l16) * 8]);
        bf16x8 a2 = *reinterpret_cast<const bf16x8*>(&Al[buf][(kg * 64 + 2 * 16 + l16) * 8]);
        bf16x8 a3 = *reinterpret_cast<const bf16x8*>(&Al[buf][(kg * 64 + 3 * 16 + l16) * 8]);
        asm volatile("s_waitcnt lgkmcnt(0)" ::: "memory");
        __builtin_amdgcn_sched_barrier(0);
        __builtin_amdgcn_s_barrier();      // all waves done reading buf c&1

        if (c + 2 < NCH) STAGE(c + 2);     // writes buf c&1 (just released)
        __builtin_amdgcn_sched_barrier(0);

        bf16x8 bfv;
        bfv[0] = f2bf(b0.x); bfv[1] = f2bf(b0.y); bfv[2] = f2bf(b0.z); bfv[3] = f2bf(b0.w);
        bfv[4] = f2bf(b1.x); bfv[5] = f2bf(b1.y); bfv[6] = f2bf(b1.z); bfv[7] = f2bf(b1.w);
        acc0 = __builtin_amdgcn_mfma_f32_16x16x32_bf16(a0, bfv, acc0, 0, 0, 0);
        acc1 = __builtin_amdgcn_mfma_f32_16x16x32_bf16(a1, bfv, acc1, 0, 0, 0);
        acc2 = __builtin_amdgcn_mfma_f32_16x16x32_bf16(a2, bfv, acc2, 0, 0, 0);
        acc3 = __builtin_amdgcn_mfma_f32_16x16x32_bf16(a3, bfv, acc3, 0, 0, 0);
    }
#undef STAGE

    const int e_lane = etile * BE + row;
    if (PARTIALS) {
        short* part = (short*)outp + (size_t)ks * (64 * D_);
        #pragma unroll
        for (int mt = 0; mt < 4; ++mt) {
            f32x4 a = (mt == 0) ? acc0 : (mt == 1) ? acc1 : (mt == 2) ? acc2 : acc3;
            int rbase = mt * 16 + kg * 4;    // D-frag: row=(lane>>4)*4+reg, col=lane&15
            #pragma unroll
            for (int r = 0; r < 4; ++r)
                part[(size_t)(rbase + r) * D_ + e_lane] = f2bf(a[r]);
        }
    } else {
        float* out = (float*)outp;
        int s = e_lane >> 9, n = e_lane & 511;
        int f = sc[n];
        #pragma unroll
        for (int mt = 0; mt < 4; ++mt) {
            f32x4 a = (mt == 0) ? acc0 : (mt == 1) ? acc1 : (mt == 2) ? acc2 : acc3;
            int rbase = mt * 16 + kg * 4;
            #pragma unroll
            for (int r = 0; r < 4; ++r) {
                int rr = rbase + r;
                int pp = rr >> 5, m = rr & 31;
                atomicAdd(&out[((pp * M_ + m) * S_ + s) * F_ + f], a[r]);
            }
        }
    }
}

// Sum KSPLIT bf16 partials (vectorized 16B reads), scatter into [2,B,R,A,S,F]
template<int KSPLIT>
__global__ void reduce_kernel(const short* __restrict__ part, const int* __restrict__ sc,
                              float* __restrict__ out) {
    int t = blockIdx.x * blockDim.x + threadIdx.x;
    if (t >= 64 * D_ / 8) return;
    int base = t * 8;
    int e0 = base % D_;
    int r  = base / D_;
    float v[8] = {0.f,0.f,0.f,0.f,0.f,0.f,0.f,0.f};
    #pragma unroll
    for (int ksp = 0; ksp < KSPLIT; ++ksp) {
        bf16x8 x = *reinterpret_cast<const bf16x8*>(&part[(size_t)ksp * (64 * D_) + base]);
        #pragma unroll
        for (int j = 0; j < 8; ++j) v[j] += bf2f(x[j]);
    }
    int pp = r >> 5, m = r & 31, s = e0 >> 9, n0 = e0 & 511;
    float* ob = &out[((pp * M_ + m) * S_ + s) * F_];
    #pragma unroll
    for (int j = 0; j < 8; ++j) ob[sc[n0 + j]] = v[j];
}

extern "C" void kernel_launch(void* const* d_in, const int* in_sizes, int n_in,
                              void* d_out, int out_size, void* d_ws, size_t ws_size,
                              hipStream_t stream) {
    const float* xr  = (const float*)d_in[0];
    const float* xi  = (const float*)d_in[1];
    const float* Cre = (const float*)d_in[2];
    const float* Cim = (const float*)d_in[3];
    const int*   sc  = (const int*)d_in[4];
    float* out = (float*)d_out;

    short* Ap = (short*)d_ws;
    const size_t partOff = 2u * 1024u * 1024u;
    const size_t need28  = partOff + 28ull * 64 * D_ * 2;
    const size_t need16  = partOff + 16ull * 64 * D_ * 2;

    prep_kernel<<<dim3((32 * D_ + 255) / 256), 256, 0, stream>>>(xr, xi, sc, Ap);
    zero_kernel<<<dim3((917504 / 4 + 255) / 256), 256, 0, stream>>>((float4*)out, 917504 / 4);

    const int rthreads = 64 * D_ / 8;
    if (ws_size >= need28) {
        short* part = (short*)((char*)d_ws + partOff);
        gemm_kernel<28, 1><<<dim3(ETILES, 28), 256, 0, stream>>>(Ap, Cre, Cim, sc, part);
        reduce_kernel<28><<<dim3((rthreads + 255) / 256), 256, 0, stream>>>(part, sc, out);
    } else if (ws_size >= need16) {
        short* part = (short*)((char*)d_ws + partOff);
        gemm_kernel<16, 1><<<dim3(ETILES, 16), 256, 0, stream>>>(Ap, Cre, Cim, sc, part);
        reduce_kernel<16><<<dim3((rthreads + 255) / 256), 256, 0, stream>>>(part, sc, out);
    } else {
        gemm_kernel<16, 0><<<dim3(ETILES, 16), 256, 0, stream>>>(Ap, Cre, Cim, sc, out);
    }
}